// Round 10
// baseline (201.910 us; speedup 1.0000x reference)
//
#include <hip/hip_runtime.h>
#include <hip/hip_bf16.h>

// Problem constants
#define BATCH 2
#define SEQ   2048
#define EMBD  1024
#define NHEAD 16
#define HDIM  64
#define QKV3  (3 * EMBD)   // 3072

// Q pre-scale folded into the QKV GEMM epilogue: (1/sqrt(HDIM)) * log2(e)
// so attention can use hardware exp2 directly (v_exp_f32 is 2^x).
#define QSCALE 0.18033688011112042f
// clamp for exp2 argument = 60 * log2(e)  (same guard as old exp clamp 60)
#define SCLAMP 86.56f

typedef __attribute__((ext_vector_type(8))) __bf16 bf16x8;
typedef __attribute__((ext_vector_type(4))) __bf16 bf16x4;
typedef __attribute__((ext_vector_type(4))) float f32x4;

__device__ __forceinline__ float fast_exp2(float x) {
#if __has_builtin(__builtin_amdgcn_exp2f)
    return __builtin_amdgcn_exp2f(x);
#else
    return exp2f(x);
#endif
}

// ---------------------------------------------------------------------------
// Fused prep: one dispatch for (a) x fp32->bf16 cast, (b) W_qkv transpose+
// cast, (c) W_out transpose+cast. Grid partition:
//   blocks [0,2048)        : cast (8 elems/thread)
//   blocks [2048,2816)     : W_qkv 64x64 transpose tiles (48 x 16)
//   blocks [2816,3072)     : W_out 64x64 transpose tiles (16 x 16)
// ---------------------------------------------------------------------------
__global__ __launch_bounds__(256) void prep_fused(
    const float* __restrict__ x,    __bf16* __restrict__ xbf,
    const float* __restrict__ Wqkv, __bf16* __restrict__ Wqkv_t,
    const float* __restrict__ Wout, __bf16* __restrict__ Wout_t)
{
    const int bid = blockIdx.x;
    const int tid = threadIdx.x;

    if (bid < 2048) {
        int i = (bid * 256 + tid) * 8;
        float4 a = *(const float4*)&x[i];
        float4 b = *(const float4*)&x[i + 4];
        bf16x8 o;
        o[0] = (__bf16)a.x; o[1] = (__bf16)a.y; o[2] = (__bf16)a.z; o[3] = (__bf16)a.w;
        o[4] = (__bf16)b.x; o[5] = (__bf16)b.y; o[6] = (__bf16)b.z; o[7] = (__bf16)b.w;
        *(bf16x8*)&xbf[i] = o;
        return;
    }

    __shared__ float t[64][65];
    const float* in; __bf16* out; int N, n0, k0;
    if (bid < 2816) {
        int tile = bid - 2048;             // W_qkv [1024,3072]: 48 n-tiles x 16 k-tiles
        N = QKV3;
        n0 = (tile % 48) * 64; k0 = (tile / 48) * 64;
        in = Wqkv; out = Wqkv_t;
    } else {
        int tile = bid - 2816;             // W_out [1024,1024]: 16 x 16
        N = EMBD;
        n0 = (tile & 15) * 64; k0 = (tile >> 4) * 64;
        in = Wout; out = Wout_t;
    }
    const int K = EMBD;
    #pragma unroll
    for (int p = 0; p < 4; p++) {
        int kr = p * 16 + (tid >> 4);
        int c4 = (tid & 15) * 4;
        float4 v = *(const float4*)&in[(size_t)(k0 + kr) * N + n0 + c4];
        t[kr][c4] = v.x; t[kr][c4 + 1] = v.y; t[kr][c4 + 2] = v.z; t[kr][c4 + 3] = v.w;
    }
    __syncthreads();
    #pragma unroll
    for (int p = 0; p < 4; p++) {
        int nr = p * 16 + (tid >> 4);
        int k4 = (tid & 15) * 4;
        bf16x4 o;
        o[0] = (__bf16)t[k4 + 0][nr];
        o[1] = (__bf16)t[k4 + 1][nr];
        o[2] = (__bf16)t[k4 + 2][nr];
        o[3] = (__bf16)t[k4 + 3][nr];
        *(bf16x4*)&out[(size_t)(n0 + nr) * K + k0 + k4] = o;
    }
}

// ---------------------------------------------------------------------------
// bf16 MFMA GEMM (B^T form): C[M,N] = A[M,K] @ Bt[N,K]^T + bias[N]
// 128x128 block tile, 4 waves (2x2), mfma_f32_16x16x32_bf16, BK=64
// ([kk][128][32] plane-split LDS), XCD-chunk swizzle, fused V^T epilogue.
// Round 10 (T3 2-phase pipeline): DOUBLE-BUFFERED LDS — tile t+1's
// global_load_lds are issued BEFORE computing tile t, so HBM/L3 latency
// hides under the MFMA phase; ONE barrier per K-step (its implicit
// vmcnt(0) drain lands after compute has covered the loads). r8 was
// serial: barrier -> stage -> barrier(drain) -> compute.
// Epilogue = r8 (unswapped MFMA; r9's swapped-operand variant regressed).
// ---------------------------------------------------------------------------
template<bool OUT_BF16>
__global__ __launch_bounds__(256) void gemm_bt_mfma(
    const __bf16* __restrict__ A,   // [M,K]
    const __bf16* __restrict__ Bt,  // [N,K]
    const float* __restrict__ bias, // [N]
    void* __restrict__ Cv,          // [M,N]
    __bf16* __restrict__ vt,        // fused V^T out (nullptr = disabled)
    int M, int N, int K, int nscale)
{
    // [buf][kk][row][32] : 2 x 16 KB per matrix = 64 KB total
    __shared__ __align__(16) __bf16 As[2][2 * 128 * 32];
    __shared__ __align__(16) __bf16 Bs[2][2 * 128 * 32];

    const int tid  = threadIdx.x;
    const int lane = tid & 63;
    const int wave = tid >> 6;
    const int wm = (wave >> 1) * 64;
    const int wn = (wave & 1) * 64;

    // XCD-chunk swizzle (requires gridDim.x % 8 == 0)
    const int hw  = (int)(blockIdx.x + gridDim.x * blockIdx.y);
    const int cpx = (int)gridDim.x >> 3;
    const int xcd = hw & 7;
    const int i_  = hw >> 3;
    const int n0 = (xcd * cpx + (i_ % cpx)) * 128;
    const int m0 = (i_ / cpx) * 128;

    const int lm = lane & 15;
    const int kq = lane >> 4;

    f32x4 acc[4][4] = {};

    // stage one BK=64 k-slab into buffer `buf`
    auto STAGE = [&](int buf, int k0) {
        #pragma unroll
        for (int r = 0; r < 4; r++) {
            int flat = r * 256 + tid;            // 0..1023
            int kk   = flat >> 9;                // k-half plane
            int row  = (flat >> 2) & 127;
            int c4   = flat & 3;                 // 16B chunk within 32-col plane
            const char* ga = (const char*)(A + (size_t)(m0 + row) * K
                                             + k0 + kk * 32 + c4 * 8);
            char* la = (char*)&As[buf][0] + flat * 16;
            __builtin_amdgcn_global_load_lds(
                (const __attribute__((address_space(1))) void*)ga,
                (__attribute__((address_space(3))) void*)la, 16, 0, 0);
            const char* gb = (const char*)(Bt + (size_t)(n0 + row) * K
                                              + k0 + kk * 32 + c4 * 8);
            char* lb = (char*)&Bs[buf][0] + flat * 16;
            __builtin_amdgcn_global_load_lds(
                (const __attribute__((address_space(1))) void*)gb,
                (__attribute__((address_space(3))) void*)lb, 16, 0, 0);
        }
    };

    STAGE(0, 0);
    __syncthreads();            // implicit vmcnt(0) drain + barrier
    int cur = 0;

    for (int k0 = 0; k0 < K; k0 += 64) {
        const bool more = (k0 + 64 < K);
        if (more) STAGE(cur ^ 1, k0 + 64);   // loads fly during compute below

        #pragma unroll
        for (int kk = 0; kk < 2; kk++) {
            bf16x8 af[4], bf[4];
            #pragma unroll
            for (int t = 0; t < 4; t++) {
                af[t] = *(const bf16x8*)&As[cur][kk * 4096 + (wm + t * 16 + lm) * 32 + kq * 8];
                bf[t] = *(const bf16x8*)&Bs[cur][kk * 4096 + (wn + t * 16 + lm) * 32 + kq * 8];
            }
            #pragma unroll
            for (int i = 0; i < 4; i++)
                #pragma unroll
                for (int j = 0; j < 4; j++)
                    acc[i][j] = __builtin_amdgcn_mfma_f32_16x16x32_bf16(
                        af[i], bf[j], acc[i][j], 0, 0, 0);
        }

        if (more) {
            __syncthreads();    // drains staged loads (latency already covered)
            cur ^= 1;
        }
    }

    const int r0 = kq * 4;
    #pragma unroll
    for (int i = 0; i < 4; i++) {
        #pragma unroll
        for (int j = 0; j < 4; j++) {
            int col = n0 + wn + j * 16 + lm;
            float bv = bias[col];
            float sc = (col < nscale) ? QSCALE : 1.0f;
            if (OUT_BF16 && vt && col >= 2 * EMBD) {
                // V region: write vt[bh][d][k] only (skip qkv)
                const int hd   = col - 2 * EMBD;        // h*64 + d
                const int rowb = m0 + wm + i * 16 + r0; // 4 consecutive rows
                const int bh   = (rowb >> 11) * 16 + (hd >> 6);
                const int d    = hd & 63;
                const int seq  = rowb & (SEQ - 1);
                bf16x4 o;
                #pragma unroll
                for (int r = 0; r < 4; r++) o[r] = (__bf16)(acc[i][j][r] + bv);
                *(bf16x4*)&vt[((size_t)bh * 64 + d) * SEQ + seq] = o;
            } else {
                #pragma unroll
                for (int r = 0; r < 4; r++) {
                    int row = m0 + wm + i * 16 + r0 + r;
                    float val = (acc[i][j][r] + bv) * sc;
                    if (OUT_BF16) ((__bf16*)Cv)[(size_t)row * N + col] = (__bf16)val;
                    else          ((float*)Cv)[(size_t)row * N + col] = val;
                }
            }
        }
    }
}

// ---------------------------------------------------------------------------
// Output projection GEMM: C = A @ Bt^T + bias, fp32 out. 64x64 tile, 4 waves
// (2x2, 32x32 each), BK=64 plane-split LDS, XCD swizzle, 1024 blocks = 4/CU.
// Round 10: same T3 2-phase double-buffer as the QKV GEMM (32 KB LDS).
// Epilogue = r8 (unswapped; r9 swap regressed).
// ---------------------------------------------------------------------------
__global__ __launch_bounds__(256) void gemm_bt_mfma64(
    const __bf16* __restrict__ A,   // [M,K]
    const __bf16* __restrict__ Bt,  // [N,K]
    const float* __restrict__ bias, // [N]
    float* __restrict__ C,          // [M,N]
    int M, int N, int K)
{
    __shared__ __align__(16) __bf16 As[2][2 * 64 * 32];   // 2 x 8 KB per matrix
    __shared__ __align__(16) __bf16 Bs[2][2 * 64 * 32];

    const int tid  = threadIdx.x;
    const int lane = tid & 63;
    const int wave = tid >> 6;
    const int wm = (wave >> 1) * 32;
    const int wn = (wave & 1) * 32;

    const int hw  = (int)(blockIdx.x + gridDim.x * blockIdx.y);
    const int cpx = (int)gridDim.x >> 3;
    const int xcd = hw & 7;
    const int i_  = hw >> 3;
    const int n0 = (xcd * cpx + (i_ % cpx)) * 64;
    const int m0 = (i_ / cpx) * 64;

    const int lm = lane & 15;
    const int kq = lane >> 4;

    f32x4 acc[2][2] = {};

    auto STAGE = [&](int buf, int k0) {
        #pragma unroll
        for (int r = 0; r < 2; r++) {
            int flat = r * 256 + tid;            // 0..511
            int kk   = flat >> 8;
            int row  = (flat >> 2) & 63;
            int c4   = flat & 3;
            const char* ga = (const char*)(A + (size_t)(m0 + row) * K
                                             + k0 + kk * 32 + c4 * 8);
            char* la = (char*)&As[buf][0] + flat * 16;
            __builtin_amdgcn_global_load_lds(
                (const __attribute__((address_space(1))) void*)ga,
                (__attribute__((address_space(3))) void*)la, 16, 0, 0);
            const char* gb = (const char*)(Bt + (size_t)(n0 + row) * K
                                              + k0 + kk * 32 + c4 * 8);
            char* lb = (char*)&Bs[buf][0] + flat * 16;
            __builtin_amdgcn_global_load_lds(
                (const __attribute__((address_space(1))) void*)gb,
                (__attribute__((address_space(3))) void*)lb, 16, 0, 0);
        }
    };

    STAGE(0, 0);
    __syncthreads();
    int cur = 0;

    for (int k0 = 0; k0 < K; k0 += 64) {
        const bool more = (k0 + 64 < K);
        if (more) STAGE(cur ^ 1, k0 + 64);

        #pragma unroll
        for (int kk = 0; kk < 2; kk++) {
            bf16x8 af[2], bf[2];
            #pragma unroll
            for (int t = 0; t < 2; t++) {
                af[t] = *(const bf16x8*)&As[cur][kk * 2048 + (wm + t * 16 + lm) * 32 + kq * 8];
                bf[t] = *(const bf16x8*)&Bs[cur][kk * 2048 + (wn + t * 16 + lm) * 32 + kq * 8];
            }
            #pragma unroll
            for (int i = 0; i < 2; i++)
                #pragma unroll
                for (int j = 0; j < 2; j++)
                    acc[i][j] = __builtin_amdgcn_mfma_f32_16x16x32_bf16(
                        af[i], bf[j], acc[i][j], 0, 0, 0);
        }

        if (more) {
            __syncthreads();
            cur ^= 1;
        }
    }

    const int r0 = kq * 4;
    #pragma unroll
    for (int i = 0; i < 2; i++) {
        #pragma unroll
        for (int j = 0; j < 2; j++) {
            int col = n0 + wn + j * 16 + lm;
            float bv = bias[col];
            #pragma unroll
            for (int r = 0; r < 4; r++) {
                int row = m0 + wm + i * 16 + r0 + r;
                C[(size_t)row * N + col] = acc[i][j][r] + bv;
            }
        }
    }
}

// ---------------------------------------------------------------------------
// K-parallel MFMA flash attention (causal), bf16 in/out, fp32 accum.
// Block = 256 threads = 4 waves; block owns 64 q-rows (4 frags/wave).
// Wave w processes k-tiles t = w, w+4, ... INDEPENDENTLY (no barriers in the
// k-loop) accumulating private unnormalized (O, l) — additive because the
// softmax has no running max (p = exp2(s), s pre-scaled by log2e/8, clamp).
// [Round 10: UNCHANGED control — best measured structure, 52.5-53.7 µs.]
//
// QK^T is computed SWAPPED: S^T = mfma(K_frag, Q_frag), so each lane holds
// P[q=c][k = jj*16 + quad*4 + r] — 4 CONSECUTIVE k of one q-row. These pack
// into one aligned 8-byte LDS store per (jj,qf) that lands exactly in the
// A-frag layout the PV readback needs (bank-uniform). Row-sums of l are
// lane-local + 2 cross-quad shuffles.
// End: 3-barrier LDS tree combine of the 4 waves' partials, then normalize.
// ---------------------------------------------------------------------------
__global__ __launch_bounds__(256) void attn_kpar_mfma(
    const __bf16* __restrict__ qkv, const __bf16* __restrict__ vt,
    __bf16* __restrict__ attn)
{
    // smem: loop phase = Pbuf[4 waves][4 qf][2048 B] = 32768 B
    //       combine    = Ored[2][64][66] f32 (33792 B) + lred[2][64] (512 B)
    __shared__ __align__(16) char smem[34304];

    const int tid  = threadIdx.x;
    const int wave = tid >> 6;
    const int lane = tid & 63;
    const int quad = lane >> 4;
    const int c    = lane & 15;

    const int bh = blockIdx.x;
    const int b  = bh >> 4;
    const int h  = bh & 15;
    const int qblk = (int)(gridDim.y - 1) - blockIdx.y;   // heavy first
    const int q0 = qblk * 64;

    const size_t base = (size_t)b * SEQ * QKV3;
    const int hoff = h * HDIM;
    const __bf16* vbase = vt + (size_t)bh * 64 * SEQ;

    // Q B-frags (pre-scaled by log2(e)/8 in the QKV GEMM epilogue)
    bf16x8 aq[4][2];
    #pragma unroll
    for (int qf = 0; qf < 4; qf++) {
        const __bf16* qrow = qkv + base +
            (size_t)(q0 + qf * 16 + c) * QKV3 + hoff + quad * 8;
        aq[qf][0] = *(const bf16x8*)(qrow);
        aq[qf][1] = *(const bf16x8*)(qrow + 32);
    }

    f32x4 acc[4][4] = {};      // [qf][dd], C-layout: col=d (lane&15), row=q (quad*4+r)
    float lpart[4] = {};       // per-lane row-sum partial for q = c (per qf)

    char* pbw = smem + wave * 8192;
    const int ntiles = qblk + 1;    // 64-k tiles covering [0, q0+63]

    for (int t = wave; t < ntiles; t += 4) {
        const int k0 = t * 64;
        const bool diag = (t == ntiles - 1);

        // S^T = K Q^T per jj (16 k-rows), exp2, pack 4 bf16 -> one b64 store
        #pragma unroll
        for (int jj = 0; jj < 4; jj++) {
            const __bf16* krow = qkv + base +
                (size_t)(k0 + jj * 16 + c) * QKV3 + EMBD + hoff + quad * 8;
            bf16x8 bk0 = *(const bf16x8*)(krow);
            bf16x8 bk1 = *(const bf16x8*)(krow + 32);
            const int kb = k0 + jj * 16 + quad * 4;   // this lane's k base (4 r's)
            const int wb = (jj >> 1) * 1024 + (((jj & 1) * 2 + (quad >> 1))) * 256
                         + c * 16 + (quad & 1) * 8;
            #pragma unroll
            for (int qf = 0; qf < 4; qf++) {
                f32x4 s = {};
                s = __builtin_amdgcn_mfma_f32_16x16x32_bf16(bk0, aq[qf][0], s, 0, 0, 0);
                s = __builtin_amdgcn_mfma_f32_16x16x32_bf16(bk1, aq[qf][1], s, 0, 0, 0);
                const int qa = q0 + qf * 16 + c;
                bf16x4 pk;
                #pragma unroll
                for (int r = 0; r < 4; r++) {
                    float p;
                    if (diag && (kb + r > qa)) p = 0.f;
                    else p = fast_exp2(fminf(s[r], SCLAMP));
                    lpart[qf] += p;
                    pk[r] = (__bf16)p;
                }
                *(bf16x4*)(pbw + qf * 2048 + wb) = pk;
            }
        }

        // O += P V : P A-frags from wave-private LDS (in-order per-wave pipe),
        // V^T B-frags direct from vt. Split by 32-k chunk to cap VGPR pressure.
        __builtin_amdgcn_s_setprio(1);
        #pragma unroll
        for (int kc = 0; kc < 2; kc++) {
            bf16x8 ap[4];
            #pragma unroll
            for (int qf = 0; qf < 4; qf++)
                ap[qf] = *(const bf16x8*)(pbw + qf * 2048 + kc * 1024 + lane * 16);
            #pragma unroll
            for (int dd = 0; dd < 4; dd++) {
                const __bf16* vr = vbase + (size_t)(dd * 16 + c) * SEQ
                                 + k0 + kc * 32 + quad * 8;
                bf16x8 bv = *(const bf16x8*)(vr);
                #pragma unroll
                for (int qf = 0; qf < 4; qf++)
                    acc[qf][dd] = __builtin_amdgcn_mfma_f32_16x16x32_bf16(
                        ap[qf], bv, acc[qf][dd], 0, 0, 0);
            }
        }
        __builtin_amdgcn_s_setprio(0);
    }

    // Full row-sums of l within wave: lane holds q=c partial; reduce across quads
    #pragma unroll
    for (int qf = 0; qf < 4; qf++) {
        float v = lpart[qf];
        v += __shfl_xor(v, 16);
        v += __shfl_xor(v, 32);
        lpart[qf] = v;
    }

    __syncthreads();   // done with Pbuf; reuse smem for the combine

    float* Ored = (float*)smem;                    // [2][64][66]
    float* lred = (float*)(smem + 33792);          // [2][64]

    if (wave < 2) {
        float* R = Ored + wave * (64 * 66);
        #pragma unroll
        for (int qf = 0; qf < 4; qf++) {
            #pragma unroll
            for (int dd = 0; dd < 4; dd++)
                #pragma unroll
                for (int r = 0; r < 4; r++)
                    R[(qf * 16 + quad * 4 + r) * 66 + dd * 16 + c] = acc[qf][dd][r];
            if (quad == 0) lred[wave * 64 + qf * 16 + c] = lpart[qf];
        }
    }
    __syncthreads();
    if (wave >= 2) {
        float* R = Ored + (wave - 2) * (64 * 66);
        #pragma unroll
        for (int qf = 0; qf < 4; qf++) {
            #pragma unroll
            for (int dd = 0; dd < 4; dd++)
                #pragma unroll
                for (int r = 0; r < 4; r++)
                    R[(qf * 16 + quad * 4 + r) * 66 + dd * 16 + c] += acc[qf][dd][r];
            if (quad == 0) lred[(wave - 2) * 64 + qf * 16 + c] += lpart[qf];
        }
    }
    __syncthreads();

    // Final: each thread does one 8-col chunk of one row; 2 iterations for 64 rows
    #pragma unroll
    for (int it = 0; it < 2; it++) {
        const int flat = it * 256 + tid;
        const int row = flat >> 3;         // 0..63
        const int cg  = flat & 7;          // 8-col group
        const float l = lred[row] + lred[64 + row];
        const float inv = 1.f / l;
        const float* R0 = Ored + row * 66 + cg * 8;
        const float* R1 = R0 + 64 * 66;
        bf16x8 o;
        #pragma unroll
        for (int i = 0; i < 8; i++) o[i] = (__bf16)((R0[i] + R1[i]) * inv);
        *(bf16x8*)&attn[((size_t)b * SEQ + q0 + row) * EMBD + hoff + cg * 8] = o;
    }
}

// ---------------------------------------------------------------------------
extern "C" void kernel_launch(void* const* d_in, const int* in_sizes, int n_in,
                              void* d_out, int out_size, void* d_ws, size_t ws_size,
                              hipStream_t stream)
{
    const float* x     = (const float*)d_in[0];  // [2,2048,1024]
    const float* W_qkv = (const float*)d_in[1];  // [1024,3072]
    const float* b_qkv = (const float*)d_in[2];  // [3072]
    const float* W_out = (const float*)d_in[3];  // [1024,1024]
    const float* b_out = (const float*)d_in[4];  // [1024]
    float* out = (float*)d_out;                  // [2,2048,1024] fp32

    const int M = BATCH * SEQ;   // 4096

    __bf16* xbf    = (__bf16*)d_ws;                          // [4096,1024]  8 MB
    __bf16* Wqkv_t = xbf    + (size_t)M * EMBD;              // [3072,1024]  6 MB
    __bf16* Wout_t = Wqkv_t + (size_t)QKV3 * EMBD;           // [1024,1024]  2 MB
    __bf16* qkv    = Wout_t + (size_t)EMBD * EMBD;           // [4096,3072] 24 MB
    __bf16* attn   = qkv    + (size_t)M * QKV3;              // [4096,1024]  8 MB
    __bf16* vtbuf  = attn   + (size_t)M * EMBD;              // [32,64,2048]  8 MB

    // 0) Fused prep: cast + both weight transposes in ONE dispatch
    prep_fused<<<3072, 256, 0, stream>>>(x, xbf, W_qkv, Wqkv_t, W_out, Wout_t);

    // 1) QKV projection (bf16 out; Q cols pre-scaled; V region written
    //    straight to vt[bh][d][k]); BK=64, 2-phase double-buffered pipeline
    {
        dim3 grid(QKV3 / 128, M / 128);   // 24 x 32 = 768 blocks (%8 == 0)
        gemm_bt_mfma<true><<<grid, 256, 0, stream>>>(
            xbf, Wqkv_t, b_qkv, qkv, vtbuf, M, QKV3, EMBD, EMBD);
    }
    // 2) K-parallel MFMA flash causal attention (64 q/block, no loop barriers)
    {
        dim3 grid(BATCH * NHEAD, SEQ / 64);
        attn_kpar_mfma<<<grid, 256, 0, stream>>>(qkv, vtbuf, attn);
    }
    // 3) Output projection (fp32 out): 64x64 tiles, BK=64, XCD swizzle,
    //    2-phase double-buffered pipeline
    {
        dim3 grid(EMBD / 64, M / 64);     // 16 x 64 = 1024 blocks (%8 == 0)
        gemm_bt_mfma64<<<grid, 256, 0, stream>>>(attn, Wout_t, b_out, out, M, EMBD, EMBD);
    }
}

// Round 11
// 183.974 us; speedup vs baseline: 1.0975x; 1.0975x over previous
//
#include <hip/hip_runtime.h>
#include <hip/hip_bf16.h>

// Problem constants
#define BATCH 2
#define SEQ   2048
#define EMBD  1024
#define NHEAD 16
#define HDIM  64
#define QKV3  (3 * EMBD)   // 3072

// Q pre-scale folded into the QKV GEMM epilogue: (1/sqrt(HDIM)) * log2(e)
// so attention can use hardware exp2 directly (v_exp_f32 is 2^x).
#define QSCALE 0.18033688011112042f
// clamp for exp2 argument = 60 * log2(e)  (same guard as old exp clamp 60)
#define SCLAMP 86.56f

typedef __attribute__((ext_vector_type(8))) __bf16 bf16x8;
typedef __attribute__((ext_vector_type(4))) __bf16 bf16x4;
typedef __attribute__((ext_vector_type(4))) float f32x4;

__device__ __forceinline__ float fast_exp2(float x) {
#if __has_builtin(__builtin_amdgcn_exp2f)
    return __builtin_amdgcn_exp2f(x);
#else
    return exp2f(x);
#endif
}

// ---------------------------------------------------------------------------
// Fused prep: one dispatch for (a) x fp32->bf16 cast, (b) W_qkv transpose+
// cast, (c) W_out transpose+cast. Grid partition:
//   blocks [0,2048)        : cast (8 elems/thread)
//   blocks [2048,2816)     : W_qkv 64x64 transpose tiles (48 x 16)
//   blocks [2816,3072)     : W_out 64x64 transpose tiles (16 x 16)
// ---------------------------------------------------------------------------
__global__ __launch_bounds__(256) void prep_fused(
    const float* __restrict__ x,    __bf16* __restrict__ xbf,
    const float* __restrict__ Wqkv, __bf16* __restrict__ Wqkv_t,
    const float* __restrict__ Wout, __bf16* __restrict__ Wout_t)
{
    const int bid = blockIdx.x;
    const int tid = threadIdx.x;

    if (bid < 2048) {
        int i = (bid * 256 + tid) * 8;
        float4 a = *(const float4*)&x[i];
        float4 b = *(const float4*)&x[i + 4];
        bf16x8 o;
        o[0] = (__bf16)a.x; o[1] = (__bf16)a.y; o[2] = (__bf16)a.z; o[3] = (__bf16)a.w;
        o[4] = (__bf16)b.x; o[5] = (__bf16)b.y; o[6] = (__bf16)b.z; o[7] = (__bf16)b.w;
        *(bf16x8*)&xbf[i] = o;
        return;
    }

    __shared__ float t[64][65];
    const float* in; __bf16* out; int N, n0, k0;
    if (bid < 2816) {
        int tile = bid - 2048;             // W_qkv [1024,3072]: 48 n-tiles x 16 k-tiles
        N = QKV3;
        n0 = (tile % 48) * 64; k0 = (tile / 48) * 64;
        in = Wqkv; out = Wqkv_t;
    } else {
        int tile = bid - 2816;             // W_out [1024,1024]: 16 x 16
        N = EMBD;
        n0 = (tile & 15) * 64; k0 = (tile >> 4) * 64;
        in = Wout; out = Wout_t;
    }
    const int K = EMBD;
    #pragma unroll
    for (int p = 0; p < 4; p++) {
        int kr = p * 16 + (tid >> 4);
        int c4 = (tid & 15) * 4;
        float4 v = *(const float4*)&in[(size_t)(k0 + kr) * N + n0 + c4];
        t[kr][c4] = v.x; t[kr][c4 + 1] = v.y; t[kr][c4 + 2] = v.z; t[kr][c4 + 3] = v.w;
    }
    __syncthreads();
    #pragma unroll
    for (int p = 0; p < 4; p++) {
        int nr = p * 16 + (tid >> 4);
        int k4 = (tid & 15) * 4;
        bf16x4 o;
        o[0] = (__bf16)t[k4 + 0][nr];
        o[1] = (__bf16)t[k4 + 1][nr];
        o[2] = (__bf16)t[k4 + 2][nr];
        o[3] = (__bf16)t[k4 + 3][nr];
        *(bf16x4*)&out[(size_t)(n0 + nr) * K + k0 + k4] = o;
    }
}

// ---------------------------------------------------------------------------
// QKV projection GEMM: C[M,N] = A[M,K] @ Bt[N,K]^T + bias[N], bf16 out.
// 128x128 block tile, BK=64 ([kk][128][32] plane-split LDS, single-buffer —
// r10's explicit double-buffer regressed, reproducing m99/m100), XCD-chunk
// swizzle, fused V^T epilogue.
// Round 11: 512 THREADS / 8 WAVES, each wave owns a 64x32 sub-tile -> acc is
// 32 AGPR instead of 64; total regs ~85 -> 4 waves/SIMD tier (was 2 at ~176
// regs). 16 waves/CU hide the load/barrier latency the counters showed
// (MfmaUtil 17%, HBM 14%, L2 19% of ceiling: pure latency-bound).
// __launch_bounds__(512,4) pins the allocator to the 128-reg tier.
// ---------------------------------------------------------------------------
__global__ __launch_bounds__(512, 4) void gemm_qkv(
    const __bf16* __restrict__ A,   // [M,K]
    const __bf16* __restrict__ Bt,  // [N,K]
    const float* __restrict__ bias, // [N]
    __bf16* __restrict__ C,         // [M,N] (Q/K regions)
    __bf16* __restrict__ vt,        // [bh][d][k] fused V^T out
    int M, int N, int K, int nscale)
{
    __shared__ __align__(16) __bf16 As[2 * 128 * 32];   // [kk][row][32]
    __shared__ __align__(16) __bf16 Bs[2 * 128 * 32];

    const int tid  = threadIdx.x;
    const int lane = tid & 63;
    const int wave = tid >> 6;          // 0..7
    const int wm = (wave >> 2) * 64;    // m-half
    const int wn = (wave & 3) * 32;     // n-quarter (32 wide)

    // XCD-chunk swizzle (requires gridDim.x % 8 == 0)
    const int hw  = (int)(blockIdx.x + gridDim.x * blockIdx.y);
    const int cpx = (int)gridDim.x >> 3;
    const int xcd = hw & 7;
    const int i_  = hw >> 3;
    const int n0 = (xcd * cpx + (i_ % cpx)) * 128;
    const int m0 = (i_ / cpx) * 128;

    const int lm = lane & 15;
    const int kq = lane >> 4;

    f32x4 acc[4][2] = {};               // wave tile 64(m) x 32(n)

    for (int k0 = 0; k0 < K; k0 += 64) {
        __syncthreads();
        #pragma unroll
        for (int r = 0; r < 2; r++) {
            int flat = r * 512 + tid;            // 0..1023
            int kk   = flat >> 9;                // k-half plane
            int row  = (flat >> 2) & 127;
            int c4   = flat & 3;                 // 16B chunk within 32-col plane
            const char* ga = (const char*)(A + (size_t)(m0 + row) * K
                                             + k0 + kk * 32 + c4 * 8);
            char* la = (char*)As + flat * 16;    // linear dest = [kk][row][c4]
            __builtin_amdgcn_global_load_lds(
                (const __attribute__((address_space(1))) void*)ga,
                (__attribute__((address_space(3))) void*)la, 16, 0, 0);
            const char* gb = (const char*)(Bt + (size_t)(n0 + row) * K
                                              + k0 + kk * 32 + c4 * 8);
            char* lb = (char*)Bs + flat * 16;
            __builtin_amdgcn_global_load_lds(
                (const __attribute__((address_space(1))) void*)gb,
                (__attribute__((address_space(3))) void*)lb, 16, 0, 0);
        }
        __syncthreads();

        #pragma unroll
        for (int kk = 0; kk < 2; kk++) {
            bf16x8 af[4], bf[2];
            #pragma unroll
            for (int t = 0; t < 4; t++)
                af[t] = *(const bf16x8*)&As[kk * 4096 + (wm + t * 16 + lm) * 32 + kq * 8];
            #pragma unroll
            for (int t = 0; t < 2; t++)
                bf[t] = *(const bf16x8*)&Bs[kk * 4096 + (wn + t * 16 + lm) * 32 + kq * 8];
            #pragma unroll
            for (int i = 0; i < 4; i++)
                #pragma unroll
                for (int j = 0; j < 2; j++)
                    acc[i][j] = __builtin_amdgcn_mfma_f32_16x16x32_bf16(
                        af[i], bf[j], acc[i][j], 0, 0, 0);
        }
    }

    const int r0 = kq * 4;
    #pragma unroll
    for (int i = 0; i < 4; i++) {
        #pragma unroll
        for (int j = 0; j < 2; j++) {
            int col = n0 + wn + j * 16 + lm;
            float bv = bias[col];
            float sc = (col < nscale) ? QSCALE : 1.0f;
            if (col >= 2 * EMBD) {
                // V region: write vt[bh][d][k] only (skip qkv)
                const int hd   = col - 2 * EMBD;        // h*64 + d
                const int rowb = m0 + wm + i * 16 + r0; // 4 consecutive rows
                const int bh   = (rowb >> 11) * 16 + (hd >> 6);
                const int d    = hd & 63;
                const int seq  = rowb & (SEQ - 1);
                bf16x4 o;
                #pragma unroll
                for (int r = 0; r < 4; r++) o[r] = (__bf16)(acc[i][j][r] + bv);
                *(bf16x4*)&vt[((size_t)bh * 64 + d) * SEQ + seq] = o;
            } else {
                #pragma unroll
                for (int r = 0; r < 4; r++) {
                    int row = m0 + wm + i * 16 + r0 + r;
                    C[(size_t)row * N + col] = (__bf16)((acc[i][j][r] + bv) * sc);
                }
            }
        }
    }
}

// ---------------------------------------------------------------------------
// Output projection GEMM: C = A @ Bt^T + bias, fp32 out. 64x64 tile, 4 waves
// (2x2, 32x32 each), BK=64 plane-split LDS (single-buffer, r8 version), XCD
// swizzle, 1024 blocks = 4/CU.
// ---------------------------------------------------------------------------
__global__ __launch_bounds__(256) void gemm_bt_mfma64(
    const __bf16* __restrict__ A,   // [M,K]
    const __bf16* __restrict__ Bt,  // [N,K]
    const float* __restrict__ bias, // [N]
    float* __restrict__ C,          // [M,N]
    int M, int N, int K)
{
    __shared__ __align__(16) __bf16 As[2 * 64 * 32];    // [kk][row][32]
    __shared__ __align__(16) __bf16 Bs[2 * 64 * 32];

    const int tid  = threadIdx.x;
    const int lane = tid & 63;
    const int wave = tid >> 6;
    const int wm = (wave >> 1) * 32;
    const int wn = (wave & 1) * 32;

    const int hw  = (int)(blockIdx.x + gridDim.x * blockIdx.y);
    const int cpx = (int)gridDim.x >> 3;
    const int xcd = hw & 7;
    const int i_  = hw >> 3;
    const int n0 = (xcd * cpx + (i_ % cpx)) * 64;
    const int m0 = (i_ / cpx) * 64;

    const int lm = lane & 15;
    const int kq = lane >> 4;

    f32x4 acc[2][2] = {};

    for (int k0 = 0; k0 < K; k0 += 64) {
        __syncthreads();
        #pragma unroll
        for (int r = 0; r < 2; r++) {
            int flat = r * 256 + tid;            // 0..511
            int kk   = flat >> 8;
            int row  = (flat >> 2) & 63;
            int c4   = flat & 3;
            const char* ga = (const char*)(A + (size_t)(m0 + row) * K
                                             + k0 + kk * 32 + c4 * 8);
            char* la = (char*)As + flat * 16;
            __builtin_amdgcn_global_load_lds(
                (const __attribute__((address_space(1))) void*)ga,
                (__attribute__((address_space(3))) void*)la, 16, 0, 0);
            const char* gb = (const char*)(Bt + (size_t)(n0 + row) * K
                                              + k0 + kk * 32 + c4 * 8);
            char* lb = (char*)Bs + flat * 16;
            __builtin_amdgcn_global_load_lds(
                (const __attribute__((address_space(1))) void*)gb,
                (__attribute__((address_space(3))) void*)lb, 16, 0, 0);
        }
        __syncthreads();

        #pragma unroll
        for (int kk = 0; kk < 2; kk++) {
            bf16x8 af[2], bf[2];
            #pragma unroll
            for (int t = 0; t < 2; t++) {
                af[t] = *(const bf16x8*)&As[kk * 2048 + (wm + t * 16 + lm) * 32 + kq * 8];
                bf[t] = *(const bf16x8*)&Bs[kk * 2048 + (wn + t * 16 + lm) * 32 + kq * 8];
            }
            #pragma unroll
            for (int i = 0; i < 2; i++)
                #pragma unroll
                for (int j = 0; j < 2; j++)
                    acc[i][j] = __builtin_amdgcn_mfma_f32_16x16x32_bf16(
                        af[i], bf[j], acc[i][j], 0, 0, 0);
        }
    }

    const int r0 = kq * 4;
    #pragma unroll
    for (int i = 0; i < 2; i++) {
        #pragma unroll
        for (int j = 0; j < 2; j++) {
            int col = n0 + wn + j * 16 + lm;
            float bv = bias[col];
            #pragma unroll
            for (int r = 0; r < 4; r++) {
                int row = m0 + wm + i * 16 + r0 + r;
                C[(size_t)row * N + col] = acc[i][j][r] + bv;
            }
        }
    }
}

// ---------------------------------------------------------------------------
// K-parallel MFMA flash attention (causal), bf16 in/out, fp32 accum.
// Block = 256 threads = 4 waves; block owns 64 q-rows (4 frags/wave).
// Wave w processes k-tiles t = w, w+4, ... INDEPENDENTLY (no barriers in the
// k-loop) accumulating private unnormalized (O, l) — additive because the
// softmax has no running max (p = exp2(s), s pre-scaled by log2e/8, clamp).
// [Round 11: UNCHANGED control — best measured structure, 52.5-53.7 µs.]
//
// QK^T is computed SWAPPED: S^T = mfma(K_frag, Q_frag), so each lane holds
// P[q=c][k = jj*16 + quad*4 + r] — 4 CONSECUTIVE k of one q-row. These pack
// into one aligned 8-byte LDS store per (jj,qf) that lands exactly in the
// A-frag layout the PV readback needs (bank-uniform). Row-sums of l are
// lane-local + 2 cross-quad shuffles.
// End: 3-barrier LDS tree combine of the 4 waves' partials, then normalize.
// ---------------------------------------------------------------------------
__global__ __launch_bounds__(256) void attn_kpar_mfma(
    const __bf16* __restrict__ qkv, const __bf16* __restrict__ vt,
    __bf16* __restrict__ attn)
{
    // smem: loop phase = Pbuf[4 waves][4 qf][2048 B] = 32768 B
    //       combine    = Ored[2][64][66] f32 (33792 B) + lred[2][64] (512 B)
    __shared__ __align__(16) char smem[34304];

    const int tid  = threadIdx.x;
    const int wave = tid >> 6;
    const int lane = tid & 63;
    const int quad = lane >> 4;
    const int c    = lane & 15;

    const int bh = blockIdx.x;
    const int b  = bh >> 4;
    const int h  = bh & 15;
    const int qblk = (int)(gridDim.y - 1) - blockIdx.y;   // heavy first
    const int q0 = qblk * 64;

    const size_t base = (size_t)b * SEQ * QKV3;
    const int hoff = h * HDIM;
    const __bf16* vbase = vt + (size_t)bh * 64 * SEQ;

    // Q B-frags (pre-scaled by log2(e)/8 in the QKV GEMM epilogue)
    bf16x8 aq[4][2];
    #pragma unroll
    for (int qf = 0; qf < 4; qf++) {
        const __bf16* qrow = qkv + base +
            (size_t)(q0 + qf * 16 + c) * QKV3 + hoff + quad * 8;
        aq[qf][0] = *(const bf16x8*)(qrow);
        aq[qf][1] = *(const bf16x8*)(qrow + 32);
    }

    f32x4 acc[4][4] = {};      // [qf][dd], C-layout: col=d (lane&15), row=q (quad*4+r)
    float lpart[4] = {};       // per-lane row-sum partial for q = c (per qf)

    char* pbw = smem + wave * 8192;
    const int ntiles = qblk + 1;    // 64-k tiles covering [0, q0+63]

    for (int t = wave; t < ntiles; t += 4) {
        const int k0 = t * 64;
        const bool diag = (t == ntiles - 1);

        // S^T = K Q^T per jj (16 k-rows), exp2, pack 4 bf16 -> one b64 store
        #pragma unroll
        for (int jj = 0; jj < 4; jj++) {
            const __bf16* krow = qkv + base +
                (size_t)(k0 + jj * 16 + c) * QKV3 + EMBD + hoff + quad * 8;
            bf16x8 bk0 = *(const bf16x8*)(krow);
            bf16x8 bk1 = *(const bf16x8*)(krow + 32);
            const int kb = k0 + jj * 16 + quad * 4;   // this lane's k base (4 r's)
            const int wb = (jj >> 1) * 1024 + (((jj & 1) * 2 + (quad >> 1))) * 256
                         + c * 16 + (quad & 1) * 8;
            #pragma unroll
            for (int qf = 0; qf < 4; qf++) {
                f32x4 s = {};
                s = __builtin_amdgcn_mfma_f32_16x16x32_bf16(bk0, aq[qf][0], s, 0, 0, 0);
                s = __builtin_amdgcn_mfma_f32_16x16x32_bf16(bk1, aq[qf][1], s, 0, 0, 0);
                const int qa = q0 + qf * 16 + c;
                bf16x4 pk;
                #pragma unroll
                for (int r = 0; r < 4; r++) {
                    float p;
                    if (diag && (kb + r > qa)) p = 0.f;
                    else p = fast_exp2(fminf(s[r], SCLAMP));
                    lpart[qf] += p;
                    pk[r] = (__bf16)p;
                }
                *(bf16x4*)(pbw + qf * 2048 + wb) = pk;
            }
        }

        // O += P V : P A-frags from wave-private LDS (in-order per-wave pipe),
        // V^T B-frags direct from vt. Split by 32-k chunk to cap VGPR pressure.
        __builtin_amdgcn_s_setprio(1);
        #pragma unroll
        for (int kc = 0; kc < 2; kc++) {
            bf16x8 ap[4];
            #pragma unroll
            for (int qf = 0; qf < 4; qf++)
                ap[qf] = *(const bf16x8*)(pbw + qf * 2048 + kc * 1024 + lane * 16);
            #pragma unroll
            for (int dd = 0; dd < 4; dd++) {
                const __bf16* vr = vbase + (size_t)(dd * 16 + c) * SEQ
                                 + k0 + kc * 32 + quad * 8;
                bf16x8 bv = *(const bf16x8*)(vr);
                #pragma unroll
                for (int qf = 0; qf < 4; qf++)
                    acc[qf][dd] = __builtin_amdgcn_mfma_f32_16x16x32_bf16(
                        ap[qf], bv, acc[qf][dd], 0, 0, 0);
            }
        }
        __builtin_amdgcn_s_setprio(0);
    }

    // Full row-sums of l within wave: lane holds q=c partial; reduce across quads
    #pragma unroll
    for (int qf = 0; qf < 4; qf++) {
        float v = lpart[qf];
        v += __shfl_xor(v, 16);
        v += __shfl_xor(v, 32);
        lpart[qf] = v;
    }

    __syncthreads();   // done with Pbuf; reuse smem for the combine

    float* Ored = (float*)smem;                    // [2][64][66]
    float* lred = (float*)(smem + 33792);          // [2][64]

    if (wave < 2) {
        float* R = Ored + wave * (64 * 66);
        #pragma unroll
        for (int qf = 0; qf < 4; qf++) {
            #pragma unroll
            for (int dd = 0; dd < 4; dd++)
                #pragma unroll
                for (int r = 0; r < 4; r++)
                    R[(qf * 16 + quad * 4 + r) * 66 + dd * 16 + c] = acc[qf][dd][r];
            if (quad == 0) lred[wave * 64 + qf * 16 + c] = lpart[qf];
        }
    }
    __syncthreads();
    if (wave >= 2) {
        float* R = Ored + (wave - 2) * (64 * 66);
        #pragma unroll
        for (int qf = 0; qf < 4; qf++) {
            #pragma unroll
            for (int dd = 0; dd < 4; dd++)
                #pragma unroll
                for (int r = 0; r < 4; r++)
                    R[(qf * 16 + quad * 4 + r) * 66 + dd * 16 + c] += acc[qf][dd][r];
            if (quad == 0) lred[(wave - 2) * 64 + qf * 16 + c] += lpart[qf];
        }
    }
    __syncthreads();

    // Final: each thread does one 8-col chunk of one row; 2 iterations for 64 rows
    #pragma unroll
    for (int it = 0; it < 2; it++) {
        const int flat = it * 256 + tid;
        const int row = flat >> 3;         // 0..63
        const int cg  = flat & 7;          // 8-col group
        const float l = lred[row] + lred[64 + row];
        const float inv = 1.f / l;
        const float* R0 = Ored + row * 66 + cg * 8;
        const float* R1 = R0 + 64 * 66;
        bf16x8 o;
        #pragma unroll
        for (int i = 0; i < 8; i++) o[i] = (__bf16)((R0[i] + R1[i]) * inv);
        *(bf16x8*)&attn[((size_t)b * SEQ + q0 + row) * EMBD + hoff + cg * 8] = o;
    }
}

// ---------------------------------------------------------------------------
extern "C" void kernel_launch(void* const* d_in, const int* in_sizes, int n_in,
                              void* d_out, int out_size, void* d_ws, size_t ws_size,
                              hipStream_t stream)
{
    const float* x     = (const float*)d_in[0];  // [2,2048,1024]
    const float* W_qkv = (const float*)d_in[1];  // [1024,3072]
    const float* b_qkv = (const float*)d_in[2];  // [3072]
    const float* W_out = (const float*)d_in[3];  // [1024,1024]
    const float* b_out = (const float*)d_in[4];  // [1024]
    float* out = (float*)d_out;                  // [2,2048,1024] fp32

    const int M = BATCH * SEQ;   // 4096

    __bf16* xbf    = (__bf16*)d_ws;                          // [4096,1024]  8 MB
    __bf16* Wqkv_t = xbf    + (size_t)M * EMBD;              // [3072,1024]  6 MB
    __bf16* Wout_t = Wqkv_t + (size_t)QKV3 * EMBD;           // [1024,1024]  2 MB
    __bf16* qkv    = Wout_t + (size_t)EMBD * EMBD;           // [4096,3072] 24 MB
    __bf16* attn   = qkv    + (size_t)M * QKV3;              // [4096,1024]  8 MB
    __bf16* vtbuf  = attn   + (size_t)M * EMBD;              // [32,64,2048]  8 MB

    // 0) Fused prep: cast + both weight transposes in ONE dispatch
    prep_fused<<<3072, 256, 0, stream>>>(x, xbf, W_qkv, Wqkv_t, W_out, Wout_t);

    // 1) QKV projection (bf16 out; Q cols pre-scaled; V region written
    //    straight to vt[bh][d][k]); BK=64, 512 threads / 8 waves (4 w/SIMD)
    {
        dim3 grid(QKV3 / 128, M / 128);   // 24 x 32 = 768 blocks (%8 == 0)
        gemm_qkv<<<grid, 512, 0, stream>>>(
            xbf, Wqkv_t, b_qkv, qkv, vtbuf, M, QKV3, EMBD, EMBD);
    }
    // 2) K-parallel MFMA flash causal attention (64 q/block, no loop barriers)
    {
        dim3 grid(BATCH * NHEAD, SEQ / 64);
        attn_kpar_mfma<<<grid, 256, 0, stream>>>(qkv, vtbuf, attn);
    }
    // 3) Output projection (fp32 out): 64x64 tiles, BK=64, XCD swizzle
    {
        dim3 grid(EMBD / 64, M / 64);     // 16 x 64 = 1024 blocks (%8 == 0)
        gemm_bt_mfma64<<<grid, 256, 0, stream>>>(attn, Wout_t, b_out, out, M, EMBD, EMBD);
    }
}